// Round 2
// baseline (892.480 us; speedup 1.0000x reference)
//
#include <hip/hip_runtime.h>
#include <math.h>

// Problem constants
#define NB  262144   // batch
#define SD  128      // STATE_DIM
#define HID 256      // HIDDEN
#define AD  8        // ACTION_DIM

typedef float v2f __attribute__((ext_vector_type(2)));
typedef float v4f __attribute__((ext_vector_type(4)));

// d_ws layout (floats)
#define W1T_OFF 0                       // [SD][HID]   W1T[k*HID+j] = W1[j*SD+k]
#define W2T_OFF (SD*HID)                // [HID][HID]  32768
#define W3P_OFF (W2T_OFF + HID*HID)     // [HID][AD] float2 pairs (u,s): 98304, 4096 floats
#define B1_OFF  (W3P_OFF + HID*2*AD)    // 102400
#define B2_OFF  (B1_OFF + HID)          // 102656
#define B3P_OFF (B2_OFF + HID)          // 102912, [AD] float2 pairs
#define WS_FLOATS (B3P_OFF + 2*AD)      // 102928 floats = 411,712 bytes

__global__ __launch_bounds__(256) void prep_weights(
    const float* __restrict__ W1, const float* __restrict__ b1,
    const float* __restrict__ W2, const float* __restrict__ b2,
    const float* __restrict__ W3, const float* __restrict__ b3,
    float* __restrict__ ws) {
  int stride = gridDim.x * blockDim.x;
  for (int i = blockIdx.x * blockDim.x + threadIdx.x; i < WS_FLOATS; i += stride) {
    float v;
    if (i < W2T_OFF) {                       // W1T
      int k = i >> 8, j = i & 255;
      v = W1[j * SD + k];
    } else if (i < W3P_OFF) {                // W2T
      int t = i - W2T_OFF;
      int k = t >> 8, j = t & 255;
      v = W2[j * HID + k];
    } else if (i < B1_OFF) {                 // W3P[k][a] = (W3[a][k], W3[a+8][k])
      int t = i - W3P_OFF;
      int k = t >> 4, a = (t >> 1) & 7, h = t & 1;
      v = W3[(a + 8 * h) * HID + k];
    } else if (i < B2_OFF) {
      v = b1[i - B1_OFF];
    } else if (i < B3P_OFF) {
      v = b2[i - B2_OFF];
    } else {                                 // B3P[a] = (b3[a], b3[a+8])
      int t = i - B3P_OFF;
      v = b3[(t >> 1) + 8 * (t & 1)];
    }
    ws[i] = v;
  }
}

// R5/R6: VALU-issue bound (59% busy, 0 MFMA, HBM 2.3%). Two levers:
//  (1) v_pk_fma_f32 with op_sel: 2 chain-steps per instruction, no splat movs.
//      op_sel picks which dword of the packed x feeds BOTH result halves, so
//      the (k,k+1) pair loaded in the float4 is consumed in place. Each acc
//      component remains a serial k-ascending IEEE-fma chain -> bit-identical.
//  (2) LDS 33792 -> 32768 B ([32][256]) lifts occupancy 4 -> 5 blocks/CU
//      (exactly 160 KiB). The 264-pad (which de-conflicted layer-3 row reads)
//      is replaced by a per-row XOR of the float4 group index (g ^ r):
//      layer-2 reads stay wave-uniform broadcasts, and layer-3's 8 row
//      addresses land on 8 distinct banks.
// (R6 = R5 resubmitted verbatim: the R5 run died in container acquire, not
//  in compile/verify — no kernel-side failure signal existed.)

// D.lo = fma(x.lo, w.lo, acc.lo); D.hi = fma(x.lo, w.hi, acc.hi)
#define PK_LO(acc, x2, w2) \
  asm("v_pk_fma_f32 %0, %1, %2, %0 op_sel:[0,0,0] op_sel_hi:[0,1,1]" \
      : "+v"(acc) : "v"(x2), "v"(w2))
// D.lo = fma(x.hi, w.lo, acc.lo); D.hi = fma(x.hi, w.hi, acc.hi)
#define PK_HI(acc, x2, w2) \
  asm("v_pk_fma_f32 %0, %1, %2, %0 op_sel:[1,0,0] op_sel_hi:[1,1,1]" \
      : "+v"(acc) : "v"(x2), "v"(w2))

// Register/LDS-resident fused MLP. 4 waves/block, 8 rows/wave (32 rows/block).
// The [32][256] LDS buffer is reused: h1 (layer-2 broadcast source), then h2
// (layer-3 source). Wave-private rows -> NO barriers anywhere.
__global__ __launch_bounds__(256, 5) void actor_fused(
    const float* __restrict__ state, const float* __restrict__ eps,
    const float* __restrict__ ws, int* __restrict__ out) {
  __shared__ float s_h[32][256];   // 32,768 B; 5 blocks/CU = 160 KiB exactly

  const int tid  = threadIdx.x;
  const int lane = tid & 63;
  const int wvu  = __builtin_amdgcn_readfirstlane(tid >> 6);  // provably uniform
  const long wrow = (long)blockIdx.x * 32 + wvu * 8;          // wave's first row

  const v4f* __restrict__ W1T4 = (const v4f*)(ws + W1T_OFF);  // [SD][64]
  const v4f* __restrict__ W2T4 = (const v4f*)(ws + W2T_OFF);  // [HID][64]
  const v2f* __restrict__ W3P  = (const v2f*)(ws + W3P_OFF);  // [HID][8]

  const float* __restrict__ xbase = state + wrow * SD;   // uniform pointer

  // ---- layer 1: h1 = relu(x @ W1^T + b1), K = 128
  // acc0[r] = cols (4*lane, 4*lane+1), acc1[r] = cols (4*lane+2, 4*lane+3)
  v2f acc0[8], acc1[8];
  #pragma unroll
  for (int r = 0; r < 8; ++r) { acc0[r] = (v2f){0.f, 0.f}; acc1[r] = (v2f){0.f, 0.f}; }

  #pragma unroll 2
  for (int k0 = 0; k0 < SD; k0 += 4) {
    v4f w0 = W1T4[(k0 + 0) * 64 + lane];
    v4f w1 = W1T4[(k0 + 1) * 64 + lane];
    v4f w2 = W1T4[(k0 + 2) * 64 + lane];
    v4f w3 = W1T4[(k0 + 3) * 64 + lane];
    v2f w0l = w0.xy, w0h = w0.zw, w1l = w1.xy, w1h = w1.zw;
    v2f w2l = w2.xy, w2h = w2.zw, w3l = w3.xy, w3h = w3.zw;
    v4f xv[8];
    #pragma unroll
    for (int r = 0; r < 8; ++r)                       // uniform address: one line
      xv[r] = *(const v4f*)(xbase + r * SD + k0);     // serves the whole wave
    #pragma unroll
    for (int r = 0; r < 8; ++r) {
      v2f x01 = xv[r].xy, x23 = xv[r].zw;
      PK_LO(acc0[r], x01, w0l); PK_LO(acc1[r], x01, w0h);   // k = k0
      PK_HI(acc0[r], x01, w1l); PK_HI(acc1[r], x01, w1h);   // k = k0+1
      PK_LO(acc0[r], x23, w2l); PK_LO(acc1[r], x23, w2h);   // k = k0+2
      PK_HI(acc0[r], x23, w3l); PK_HI(acc1[r], x23, w3h);   // k = k0+3
    }
  }

  // bias + relu -> wave-private LDS rows, float4-group g stored at (g ^ r)
  {
    v4f bb = ((const v4f*)(ws + B1_OFF))[lane];
    #pragma unroll
    for (int r = 0; r < 8; ++r) {
      v4f hv;
      hv.x = acc0[r].x + bb.x; hv.y = acc0[r].y + bb.y;
      hv.z = acc1[r].x + bb.z; hv.w = acc1[r].y + bb.w;
      hv.x = hv.x > 0.0f ? hv.x : 0.0f;
      hv.y = hv.y > 0.0f ? hv.y : 0.0f;
      hv.z = hv.z > 0.0f ? hv.z : 0.0f;
      hv.w = hv.w > 0.0f ? hv.w : 0.0f;
      *(v4f*)&s_h[wvu * 8 + r][(lane ^ r) << 2] = hv;
    }
  }

  // ---- layer 2: h2 = relu(h1 @ W2^T + b2), K = 256
  #pragma unroll
  for (int r = 0; r < 8; ++r) { acc0[r] = (v2f){0.f, 0.f}; acc1[r] = (v2f){0.f, 0.f}; }

  #pragma unroll 2
  for (int k0 = 0; k0 < HID; k0 += 4) {
    v4f w0 = W2T4[(k0 + 0) * 64 + lane];
    v4f w1 = W2T4[(k0 + 1) * 64 + lane];
    v4f w2 = W2T4[(k0 + 2) * 64 + lane];
    v4f w3 = W2T4[(k0 + 3) * 64 + lane];
    v2f w0l = w0.xy, w0h = w0.zw, w1l = w1.xy, w1h = w1.zw;
    v2f w2l = w2.xy, w2h = w2.zw, w3l = w3.xy, w3h = w3.zw;
    v4f xv[8];
    #pragma unroll
    for (int r = 0; r < 8; ++r)                       // uniform LDS address ->
      xv[r] = *(const v4f*)&s_h[wvu * 8 + r][(((k0 >> 2) ^ r) << 2)];  // broadcast
    #pragma unroll
    for (int r = 0; r < 8; ++r) {
      v2f x01 = xv[r].xy, x23 = xv[r].zw;
      PK_LO(acc0[r], x01, w0l); PK_LO(acc1[r], x01, w0h);
      PK_HI(acc0[r], x01, w1l); PK_HI(acc1[r], x01, w1h);
      PK_LO(acc0[r], x23, w2l); PK_LO(acc1[r], x23, w2h);
      PK_HI(acc0[r], x23, w3l); PK_HI(acc1[r], x23, w3h);
    }
  }

  // bias + relu -> h2 into the SAME LDS rows (all h1 reads done, program order)
  {
    v4f bb = ((const v4f*)(ws + B2_OFF))[lane];
    #pragma unroll
    for (int r = 0; r < 8; ++r) {
      v4f hv;
      hv.x = acc0[r].x + bb.x; hv.y = acc0[r].y + bb.y;
      hv.z = acc1[r].x + bb.z; hv.w = acc1[r].y + bb.w;
      hv.x = hv.x > 0.0f ? hv.x : 0.0f;
      hv.y = hv.y > 0.0f ? hv.y : 0.0f;
      hv.z = hv.z > 0.0f ? hv.z : 0.0f;
      hv.w = hv.w > 0.0f ? hv.w : 0.0f;
      *(v4f*)&s_h[wvu * 8 + r][(lane ^ r) << 2] = hv;
    }
  }

  // ---- layer 3 (K=256, N=16) + epilogue. Lane -> (row = lane>>3, action = lane&7),
  // u in accus.x, s in accus.y; both chains serial k-ascending (matches sgemm).
  {
    const int r3 = lane >> 3;
    const int a  = lane & 7;
    const float* __restrict__ h2row = &s_h[wvu * 8 + r3][0];
    v2f accus = (v2f){0.f, 0.f};
    #pragma unroll 2
    for (int k0 = 0; k0 < HID; k0 += 4) {
      const int col = ((k0 >> 2) ^ r3) << 2;          // XOR layout; 8 rows -> 8 banks
      v2f ha = *(const v2f*)(h2row + col);            // k0, k0+1 (8-lane broadcast)
      v2f hb = *(const v2f*)(h2row + col + 2);        // k0+2, k0+3
      v2f wp0 = W3P[(k0 + 0) * 8 + a];
      v2f wp1 = W3P[(k0 + 1) * 8 + a];
      v2f wp2 = W3P[(k0 + 2) * 8 + a];
      v2f wp3 = W3P[(k0 + 3) * 8 + a];
      PK_LO(accus, ha, wp0);   // accu += ha.x*wp0.x ; accs += ha.x*wp0.y
      PK_HI(accus, ha, wp1);   // accu += ha.y*wp1.x ; accs += ha.y*wp1.y
      PK_LO(accus, hb, wp2);
      PK_HI(accus, hb, wp3);
    }
    v2f b3p = ((const v2f*)(ws + B3P_OFF))[a];
    float nu = accus.x + b3p.x;
    float ns = accus.y + b3p.y;

    long grow = wrow + r3;
    float sa = fabsf(ns);
    float ev = eps[grow * AD + a];                // coalesced: base + lane
    float t  = __fmul_rn(sa, ev);                 // separately-rounded mul
    float z  = __fadd_rn(nu, t);                  // separately-rounded add
    float e  = (float)exp(-(double)z);            // correctly-rounded expf near boundary
    float d  = __fadd_rn(1.0f, e);
    float act = 1.0f / d;
    float q  = act * 8.0f;                        // exact
    float wq = __fadd_rn(q, 1.0f);
    out[grow * AD + a] = (int)wq;                 // truncation, as astype(int32)
  }
}

extern "C" void kernel_launch(void* const* d_in, const int* in_sizes, int n_in,
                              void* d_out, int out_size, void* d_ws, size_t ws_size,
                              hipStream_t stream) {
  const float* state = (const float*)d_in[0];
  const float* W1    = (const float*)d_in[1];
  const float* b1    = (const float*)d_in[2];
  const float* W2    = (const float*)d_in[3];
  const float* b2    = (const float*)d_in[4];
  const float* W3    = (const float*)d_in[5];
  const float* b3    = (const float*)d_in[6];
  const float* eps   = (const float*)d_in[7];
  int*   out = (int*)d_out;
  float* ws  = (float*)d_ws;   // 411,712 bytes; rebuilt every launch

  hipLaunchKernelGGL(prep_weights, dim3(128), dim3(256), 0, stream,
                     W1, b1, W2, b2, W3, b3, ws);
  hipLaunchKernelGGL(actor_fused, dim3(NB / 32), dim3(256), 0, stream,
                     state, eps, ws, out);
}